// Round 1
// baseline (644.810 us; speedup 1.0000x reference)
//
#include <hip/hip_runtime.h>

// Problem constants
#define NUM_Q 8
#define BN    8192      // B*N tokens
#define D     512
#define C     1024

// d_out layout (floats): [quantized_out | indices(as float) | losses]
#define QOUT_OFF 0
#define IDX_OFF  (BN * D)
#define LOSS_OFF (IDX_OFF + BN * NUM_Q)

// d_ws layout (bytes): packed f16 codebook rows [NUM_Q*C][512 hi | 512 lo], then e2
#define CBP_OFF_B 0
#define E2_OFF_B  (NUM_Q * C * 1024 * 2)   // 16 MB

typedef _Float16 f16x8 __attribute__((ext_vector_type(8)));
typedef _Float16 f16x4 __attribute__((ext_vector_type(4)));
typedef float    f32x4 __attribute__((ext_vector_type(4)));

__device__ __forceinline__ unsigned fkey(float f) {
    unsigned u = __float_as_uint(f);
    return (u & 0x80000000u) ? ~u : (u | 0x80000000u);
}
__device__ __forceinline__ unsigned long long u64min(unsigned long long a, unsigned long long b) {
    return a < b ? a : b;
}
__device__ __forceinline__ unsigned long long shfl_xor_u64(unsigned long long v, int m) {
    int lo = __shfl_xor((int)(unsigned)v, m, 64);
    int hi = __shfl_xor((int)(unsigned)(v >> 32), m, 64);
    return ((unsigned long long)(unsigned)hi << 32) | (unsigned)lo;
}

// ---------------------------------------------------------------------------
// prep: per codebook row, write packed f16 hi|lo row (1024 f16) + e2 (from f32).
// One wave per row; also zero the loss outputs.
// ---------------------------------------------------------------------------
__global__ __launch_bounds__(256) void rvq_prep(const float* __restrict__ cbs,
                                                _Float16* __restrict__ cbp,
                                                float* __restrict__ e2ws,
                                                float* __restrict__ out) {
    const int row  = blockIdx.x * 4 + (threadIdx.x >> 6);
    const int lane = threadIdx.x & 63;
    const float* p = cbs + (size_t)row * D + lane * 8;
    float4 a = *(const float4*)p;
    float4 b = *(const float4*)(p + 4);
    float av[8] = {a.x, a.y, a.z, a.w, b.x, b.y, b.z, b.w};
    f16x8 h, l;
    float ss = 0.f;
#pragma unroll
    for (int i = 0; i < 8; ++i) {
        _Float16 hi = (_Float16)av[i];
        h[i] = hi;
        l[i] = (_Float16)(av[i] - (float)hi);
        ss += av[i] * av[i];
    }
    _Float16* dst = cbp + (size_t)row * 1024;
    *(f16x8*)(dst + lane * 8)       = h;
    *(f16x8*)(dst + 512 + lane * 8) = l;
#pragma unroll
    for (int off = 32; off >= 1; off >>= 1) ss += __shfl_xor(ss, off, 64);
    if (lane == 0) e2ws[row] = ss;
    if (blockIdx.x == 0 && threadIdx.x < NUM_Q) out[LOSS_OFF + threadIdx.x] = 0.0f;
}

// ---------------------------------------------------------------------------
// fused persistent RVQ: 256 WGs x 32 tokens, residual resident in VGPRs.
// Per layer: residual -> swizzled f16 hi/lo A in LDS; dots vs all 1024
// codewords (B fragments loaded global->reg, no barriers in hot loop);
// in-LDS argmin; in-register residual update; loss + index emit.
// ---------------------------------------------------------------------------
__global__ __launch_bounds__(512, 2) void rvq_fused(
    const float* __restrict__ x, const float* __restrict__ cbs,
    const _Float16* __restrict__ cbp, const float* __restrict__ e2ws,
    float* __restrict__ out)
{
    // A_hi [0,32KB) | A_lo [32KB,64KB); epilogue aliases argmin scratch (barrier-guarded)
    __shared__ __align__(16) unsigned char smem[65536];

    const int tid  = threadIdx.x;
    const int lane = tid & 63;
    const int wv   = tid >> 6;     // wave 0..7 -> codeword cols [wv*128, wv*128+128)
    const int lm   = lane & 15;
    const int lq   = lane >> 4;
    const int tl   = tid >> 4;     // token 0..31 within WG
    const int g    = tid & 15;     // owns k = g*4 + 64*j, j=0..7 (float4 granules)
    const int tok0 = blockIdx.x * 32;

    // swizzled A byte address: row*1024 + 2*k, XOR spreads rows over bank slots
    auto aab = [](int row, int kbyte) -> unsigned {
        return (((unsigned)row << 10) + (unsigned)kbyte) ^ (unsigned)((row & 7) << 4);
    };

    // residual in registers: 32 f32/thread as 8x float4
    float4 r4[8];
    {
        const float* xr = x + (size_t)(tok0 + tl) * D + g * 4;
#pragma unroll
        for (int j = 0; j < 8; ++j) r4[j] = *(const float4*)(xr + j * 64);
    }

    unsigned long long* red = (unsigned long long*)smem;   // [8][32] after barrier

    for (int q = 0; q < NUM_Q; ++q) {
        // ---- build A (f16 hi/lo, swizzled) from residual regs ----
#pragma unroll
        for (int j = 0; j < 8; ++j) {
            float4 v = r4[j];
            f16x4 h, l;
            h[0] = (_Float16)v.x; l[0] = (_Float16)(v.x - (float)h[0]);
            h[1] = (_Float16)v.y; l[1] = (_Float16)(v.y - (float)h[1]);
            h[2] = (_Float16)v.z; l[2] = (_Float16)(v.z - (float)h[2]);
            h[3] = (_Float16)v.w; l[3] = (_Float16)(v.w - (float)h[3]);
            unsigned b = aab(tl, (g * 4 + j * 64) * 2);
            *(f16x4*)(smem + b)         = h;
            *(f16x4*)(smem + 32768 + b) = l;
        }
        __syncthreads();

        // ---- per-wave B row pointers (packed hi|lo rows, lo = +512 elems imm) ----
        const _Float16* bp[8];
#pragma unroll
        for (int nt = 0; nt < 8; ++nt)
            bp[nt] = cbp + (((size_t)(q * C + wv * 128 + nt * 16 + lm)) << 10) + lq * 8;

        f32x4 acc[2][8];
#pragma unroll
        for (int mt = 0; mt < 2; ++mt)
#pragma unroll
            for (int nt = 0; nt < 8; ++nt)
                acc[mt][nt] = (f32x4){0.f, 0.f, 0.f, 0.f};

        // ---- barrier-free K loop: 768 MFMA + 256 global loads + 64 ds_reads ----
#pragma unroll
        for (int kb = 0; kb < 16; ++kb) {
            unsigned b0 = aab(lm,      kb * 64 + lq * 16);
            unsigned b1 = aab(16 + lm, kb * 64 + lq * 16);
            f16x8 ah0 = *(const f16x8*)(smem + b0);
            f16x8 ah1 = *(const f16x8*)(smem + b1);
            f16x8 al0 = *(const f16x8*)(smem + 32768 + b0);
            f16x8 al1 = *(const f16x8*)(smem + 32768 + b1);
#pragma unroll
            for (int nt = 0; nt < 8; ++nt) {
                f16x8 bh = *(const f16x8*)(bp[nt] + kb * 32);
                f16x8 bl = *(const f16x8*)(bp[nt] + 512 + kb * 32);
                // per-accumulator order hh, hl, lh per kb (bit-matches prior kernel)
                acc[0][nt] = __builtin_amdgcn_mfma_f32_16x16x32_f16(ah0, bh, acc[0][nt], 0, 0, 0);
                acc[1][nt] = __builtin_amdgcn_mfma_f32_16x16x32_f16(ah1, bh, acc[1][nt], 0, 0, 0);
                acc[0][nt] = __builtin_amdgcn_mfma_f32_16x16x32_f16(ah0, bl, acc[0][nt], 0, 0, 0);
                acc[1][nt] = __builtin_amdgcn_mfma_f32_16x16x32_f16(ah1, bl, acc[1][nt], 0, 0, 0);
                acc[0][nt] = __builtin_amdgcn_mfma_f32_16x16x32_f16(al0, bh, acc[0][nt], 0, 0, 0);
                acc[1][nt] = __builtin_amdgcn_mfma_f32_16x16x32_f16(al1, bh, acc[1][nt], 0, 0, 0);
            }
        }
        __syncthreads();   // all waves done reading A; red may alias it now

        // ---- scores + per-token argmin over this wave's 128 cols ----
        const float* e2q = e2ws + q * C;
        float e2v[8];
#pragma unroll
        for (int nt = 0; nt < 8; ++nt) e2v[nt] = e2q[wv * 128 + nt * 16 + lm];

        unsigned long long best[2][4];
#pragma unroll
        for (int mt = 0; mt < 2; ++mt)
#pragma unroll
            for (int r = 0; r < 4; ++r) best[mt][r] = ~0ull;

#pragma unroll
        for (int mt = 0; mt < 2; ++mt)
#pragma unroll
            for (int nt = 0; nt < 8; ++nt) {
                unsigned col = (unsigned)(wv * 128 + nt * 16 + lm);
#pragma unroll
                for (int r = 0; r < 4; ++r) {
                    float s = e2v[nt] - 2.0f * acc[mt][nt][r];
                    unsigned long long p = ((unsigned long long)fkey(s) << 32) | col;
                    best[mt][r] = u64min(best[mt][r], p);
                }
            }
#pragma unroll
        for (int mt = 0; mt < 2; ++mt)
#pragma unroll
            for (int r = 0; r < 4; ++r) {
#pragma unroll
                for (int off = 1; off < 16; off <<= 1)
                    best[mt][r] = u64min(best[mt][r], shfl_xor_u64(best[mt][r], off));
                if (lm == 0) red[wv * 32 + mt * 16 + lq * 4 + r] = best[mt][r];
            }
        __syncthreads();
        if (tid < 32) {
            unsigned long long p = red[tid];
#pragma unroll
            for (int w = 1; w < 8; ++w) p = u64min(p, red[w * 32 + tid]);
            red[tid] = p;
        }
        __syncthreads();
        const unsigned bidx = (unsigned)(red[tl] & 0xffffffffull);

        // ---- update residual in regs, emit index, accumulate loss ----
        const float* cw = cbs + ((size_t)q * C + bidx) * D + g * 4;
        float ss = 0.f;
#pragma unroll
        for (int j = 0; j < 8; ++j) {
            float4 c = *(const float4*)(cw + j * 64);
            float4 v = r4[j];
            v.x -= c.x; v.y -= c.y; v.z -= c.z; v.w -= c.w;
            r4[j] = v;
            ss += v.x * v.x + v.y * v.y + v.z * v.z + v.w * v.w;
        }
        if (g == 0) out[IDX_OFF + (size_t)(tok0 + tl) * NUM_Q + q] = (float)bidx;
#pragma unroll
        for (int off = 32; off >= 1; off >>= 1) ss += __shfl_xor(ss, off, 64);
        if (lane == 0) atomicAdd(out + LOSS_OFF + q, ss * (1.0f / ((float)BN * (float)D)));
        __syncthreads();   // protect red/A before next layer's build
    }

    // ---- finalize: quantized_out = x - residual_final ----
    {
        const float* xr = x + (size_t)(tok0 + tl) * D + g * 4;
        float* qo = out + QOUT_OFF + (size_t)(tok0 + tl) * D + g * 4;
#pragma unroll
        for (int j = 0; j < 8; ++j) {
            float4 xv = *(const float4*)(xr + j * 64);
            float4 v  = r4[j];
            *(float4*)(qo + j * 64) =
                make_float4(xv.x - v.x, xv.y - v.y, xv.z - v.z, xv.w - v.w);
        }
    }
}

extern "C" void kernel_launch(void* const* d_in, const int* in_sizes, int n_in,
                              void* d_out, int out_size, void* d_ws, size_t ws_size,
                              hipStream_t stream) {
    const float* x   = (const float*)d_in[0];
    const float* cbs = (const float*)d_in[1];
    float* out = (float*)d_out;
    _Float16* cbp = (_Float16*)((char*)d_ws + CBP_OFF_B);
    float* e2ws   = (float*)((char*)d_ws + E2_OFF_B);

    hipLaunchKernelGGL(rvq_prep,  dim3(NUM_Q * C / 4), dim3(256), 0, stream, cbs, cbp, e2ws, out);
    hipLaunchKernelGGL(rvq_fused, dim3(BN / 32),       dim3(512), 0, stream, x, cbs, cbp, e2ws, out);
}

// Round 2
// 528.400 us; speedup vs baseline: 1.2203x; 1.2203x over previous
//
#include <hip/hip_runtime.h>

// Problem constants
#define NUM_Q 8
#define BN    8192      // B*N tokens
#define D     512
#define C     1024

// d_out layout (floats): [quantized_out | indices(as float) | losses]
#define QOUT_OFF 0
#define IDX_OFF  (BN * D)
#define LOSS_OFF (IDX_OFF + BN * NUM_Q)

// d_ws layout (bytes):
//   cbp: fragment-major packed f16 codebook, per layer q (1,048,576 f16 elems = 2MB):
//     elem offset = q*1048576 + colblock*16384 + kb*1024 + {hi:0|lo:512} + (c&15)*32 + k_in
//     (colblock = c>>4 : 16 codewords; kb = K/32 slice; each hi/lo blob is a
//      contiguous 1KB MFMA fragment read by one wave in one dwordx4 instruction)
//   e2: [NUM_Q*C] float at 16MB
#define CBP_OFF_B 0
#define E2_OFF_B  (NUM_Q * C * 1024 * 2)   // 16 MB

typedef _Float16 f16x8 __attribute__((ext_vector_type(8)));
typedef _Float16 f16x4 __attribute__((ext_vector_type(4)));
typedef float    f32x4 __attribute__((ext_vector_type(4)));

__device__ __forceinline__ unsigned fkey(float f) {
    unsigned u = __float_as_uint(f);
    return (u & 0x80000000u) ? ~u : (u | 0x80000000u);
}
__device__ __forceinline__ unsigned long long u64min(unsigned long long a, unsigned long long b) {
    return a < b ? a : b;
}
__device__ __forceinline__ unsigned long long shfl_xor_u64(unsigned long long v, int m) {
    int lo = __shfl_xor((int)(unsigned)v, m, 64);
    int hi = __shfl_xor((int)(unsigned)(v >> 32), m, 64);
    return ((unsigned long long)(unsigned)hi << 32) | (unsigned)lo;
}

// ---------------------------------------------------------------------------
// prep: per codebook row, split f32 -> f16 hi/lo into fragment-major layout,
// compute e2. One wave per row; also zero the loss outputs.
// ---------------------------------------------------------------------------
__global__ __launch_bounds__(256) void rvq_prep(const float* __restrict__ cbs,
                                                _Float16* __restrict__ cbp,
                                                float* __restrict__ e2ws,
                                                float* __restrict__ out) {
    const int row  = blockIdx.x * 4 + (threadIdx.x >> 6);
    const int lane = threadIdx.x & 63;
    const float* p = cbs + (size_t)row * D + lane * 8;
    float4 a = *(const float4*)p;
    float4 b = *(const float4*)(p + 4);
    float av[8] = {a.x, a.y, a.z, a.w, b.x, b.y, b.z, b.w};
    f16x8 h, l;
    float ss = 0.f;
#pragma unroll
    for (int i = 0; i < 8; ++i) {
        _Float16 hi = (_Float16)av[i];
        h[i] = hi;
        l[i] = (_Float16)(av[i] - (float)hi);
        ss += av[i] * av[i];
    }
    const int qq = row >> 10;
    const int c  = row & 1023;
    // lane owns k = lane*8 .. lane*8+7  ->  kb = lane>>2, k_in = (lane&3)*8
    _Float16* dst = cbp + (size_t)qq * 1048576 + (c >> 4) * 16384
                  + (lane >> 2) * 1024 + (c & 15) * 32 + (lane & 3) * 8;
    *(f16x8*)dst         = h;
    *(f16x8*)(dst + 512) = l;
#pragma unroll
    for (int off = 32; off >= 1; off >>= 1) ss += __shfl_xor(ss, off, 64);
    if (lane == 0) e2ws[row] = ss;
    if (blockIdx.x == 0 && threadIdx.x < NUM_Q) out[LOSS_OFF + threadIdx.x] = 0.0f;
}

// ---------------------------------------------------------------------------
// fused persistent RVQ: 256 WGs x 32 tokens, residual resident in VGPRs.
// Per layer: residual -> swizzled f16 hi/lo A in LDS; dots vs all 1024
// codewords, B fragments register-double-buffered from fragment-major global
// (contiguous 1KB per load, half-kb pipeline depth); in-LDS argmin;
// in-register residual update; loss + index emit.
// ---------------------------------------------------------------------------
__global__ __launch_bounds__(512, 2) void rvq_fused(
    const float* __restrict__ x, const float* __restrict__ cbs,
    const _Float16* __restrict__ cbp, const float* __restrict__ e2ws,
    float* __restrict__ out)
{
    // A_hi [0,32KB) | A_lo [32KB,64KB); epilogue aliases argmin scratch (barrier-guarded)
    __shared__ __align__(16) unsigned char smem[65536];

    const int tid  = threadIdx.x;
    const int lane = tid & 63;
    const int wv   = tid >> 6;     // wave 0..7 -> codeword cols [wv*128, wv*128+128)
    const int lm   = lane & 15;
    const int lq   = lane >> 4;
    const int tl   = tid >> 4;     // token 0..31 within WG
    const int g    = tid & 15;     // owns k = g*4 + 64*j, j=0..7 (float4 granules)
    const int tok0 = blockIdx.x * 32;

    // swizzled A byte address: row*1024 + 2*k, XOR spreads rows over bank slots
    auto aab = [](int row, int kbyte) -> unsigned {
        return (((unsigned)row << 10) + (unsigned)kbyte) ^ (unsigned)((row & 7) << 4);
    };

    // residual in registers: 32 f32/thread as 8x float4
    float4 r4[8];
    {
        const float* xr = x + (size_t)(tok0 + tl) * D + g * 4;
#pragma unroll
        for (int j = 0; j < 8; ++j) r4[j] = *(const float4*)(xr + j * 64);
    }

    unsigned long long* red = (unsigned long long*)smem;   // [8][32] after barrier

    // wave's B base: first colblock (wv*8); lane's fragment slot (row lm, k lq*8)
    const _Float16* bq = cbp + (size_t)(wv * 8) * 16384 + lm * 32 + lq * 8;

    f16x8 pbA[4][2], pbB[4][2];   // [colblock-in-group][hi/lo] register double buffer

    auto LOADB = [&](f16x8 (&buf)[4][2], int eoff) {
#pragma unroll
        for (int j = 0; j < 4; ++j) {
            const _Float16* p = bq + eoff + j * 16384;
            buf[j][0] = *(const f16x8*)(p);
            buf[j][1] = *(const f16x8*)(p + 512);
        }
    };

    LOADB(pbA, 0);   // q=0, kb=0, group 0 prologue

    for (int q = 0; q < NUM_Q; ++q) {
        // ---- build A (f16 hi/lo, swizzled) from residual regs ----
#pragma unroll
        for (int j = 0; j < 8; ++j) {
            float4 v = r4[j];
            f16x4 h, l;
            h[0] = (_Float16)v.x; l[0] = (_Float16)(v.x - (float)h[0]);
            h[1] = (_Float16)v.y; l[1] = (_Float16)(v.y - (float)h[1]);
            h[2] = (_Float16)v.z; l[2] = (_Float16)(v.z - (float)h[2]);
            h[3] = (_Float16)v.w; l[3] = (_Float16)(v.w - (float)h[3]);
            unsigned b = aab(tl, (g * 4 + j * 64) * 2);
            *(f16x4*)(smem + b)         = h;
            *(f16x4*)(smem + 32768 + b) = l;
        }
        __syncthreads();

        f32x4 acc[2][8];
#pragma unroll
        for (int mt = 0; mt < 2; ++mt)
#pragma unroll
            for (int nt = 0; nt < 8; ++nt)
                acc[mt][nt] = (f32x4){0.f, 0.f, 0.f, 0.f};

        const int qb = q * 1048576;

        // ---- pipelined K loop: per kb, 2 half-steps of {8 loads | 24 MFMA} ----
#pragma unroll
        for (int kb = 0; kb < 16; ++kb) {
            unsigned b0 = aab(lm,      kb * 64 + lq * 16);
            unsigned b1 = aab(16 + lm, kb * 64 + lq * 16);
            f16x8 ah0 = *(const f16x8*)(smem + b0);
            f16x8 ah1 = *(const f16x8*)(smem + b1);
            f16x8 al0 = *(const f16x8*)(smem + 32768 + b0);
            f16x8 al1 = *(const f16x8*)(smem + 32768 + b1);

            LOADB(pbB, qb + 4 * 16384 + kb * 1024);          // group 1, this kb

#pragma unroll
            for (int j = 0; j < 4; ++j) {                    // group 0 from pbA
                acc[0][j] = __builtin_amdgcn_mfma_f32_16x16x32_f16(ah0, pbA[j][0], acc[0][j], 0, 0, 0);
                acc[1][j] = __builtin_amdgcn_mfma_f32_16x16x32_f16(ah1, pbA[j][0], acc[1][j], 0, 0, 0);
                acc[0][j] = __builtin_amdgcn_mfma_f32_16x16x32_f16(ah0, pbA[j][1], acc[0][j], 0, 0, 0);
                acc[1][j] = __builtin_amdgcn_mfma_f32_16x16x32_f16(ah1, pbA[j][1], acc[1][j], 0, 0, 0);
                acc[0][j] = __builtin_amdgcn_mfma_f32_16x16x32_f16(al0, pbA[j][0], acc[0][j], 0, 0, 0);
                acc[1][j] = __builtin_amdgcn_mfma_f32_16x16x32_f16(al1, pbA[j][0], acc[1][j], 0, 0, 0);
            }

            // next kb's group 0 (or next layer's first chunk at kb==15;
            // q==7 tail reads unused bytes inside the 256MB workspace)
            LOADB(pbA, (kb < 15) ? (qb + (kb + 1) * 1024) : (qb + 1048576));

#pragma unroll
            for (int j = 0; j < 4; ++j) {                    // group 1 from pbB
                acc[0][4 + j] = __builtin_amdgcn_mfma_f32_16x16x32_f16(ah0, pbB[j][0], acc[0][4 + j], 0, 0, 0);
                acc[1][4 + j] = __builtin_amdgcn_mfma_f32_16x16x32_f16(ah1, pbB[j][0], acc[1][4 + j], 0, 0, 0);
                acc[0][4 + j] = __builtin_amdgcn_mfma_f32_16x16x32_f16(ah0, pbB[j][1], acc[0][4 + j], 0, 0, 0);
                acc[1][4 + j] = __builtin_amdgcn_mfma_f32_16x16x32_f16(ah1, pbB[j][1], acc[1][4 + j], 0, 0, 0);
                acc[0][4 + j] = __builtin_amdgcn_mfma_f32_16x16x32_f16(al0, pbB[j][0], acc[0][4 + j], 0, 0, 0);
                acc[1][4 + j] = __builtin_amdgcn_mfma_f32_16x16x32_f16(al1, pbB[j][0], acc[1][4 + j], 0, 0, 0);
            }
        }
        __syncthreads();   // all waves done reading A; red may alias it now

        // ---- scores + per-token argmin over this wave's 128 cols ----
        const float* e2q = e2ws + q * C;
        float e2v[8];
#pragma unroll
        for (int nt = 0; nt < 8; ++nt) e2v[nt] = e2q[wv * 128 + nt * 16 + lm];

        unsigned long long best[2][4];
#pragma unroll
        for (int mt = 0; mt < 2; ++mt)
#pragma unroll
            for (int r = 0; r < 4; ++r) best[mt][r] = ~0ull;

#pragma unroll
        for (int mt = 0; mt < 2; ++mt)
#pragma unroll
            for (int nt = 0; nt < 8; ++nt) {
                unsigned col = (unsigned)(wv * 128 + nt * 16 + lm);
#pragma unroll
                for (int r = 0; r < 4; ++r) {
                    float s = e2v[nt] - 2.0f * acc[mt][nt][r];
                    unsigned long long p = ((unsigned long long)fkey(s) << 32) | col;
                    best[mt][r] = u64min(best[mt][r], p);
                }
            }
#pragma unroll
        for (int mt = 0; mt < 2; ++mt)
#pragma unroll
            for (int r = 0; r < 4; ++r) {
#pragma unroll
                for (int off = 1; off < 16; off <<= 1)
                    best[mt][r] = u64min(best[mt][r], shfl_xor_u64(best[mt][r], off));
                if (lm == 0) red[wv * 32 + mt * 16 + lq * 4 + r] = best[mt][r];
            }
        __syncthreads();
        if (tid < 32) {
            unsigned long long p = red[tid];
#pragma unroll
            for (int w = 1; w < 8; ++w) p = u64min(p, red[w * 32 + tid]);
            red[tid] = p;
        }
        __syncthreads();
        const unsigned bidx = (unsigned)(red[tl] & 0xffffffffull);

        // ---- update residual in regs, emit index, accumulate loss ----
        const float* cw = cbs + ((size_t)q * C + bidx) * D + g * 4;
        float ss = 0.f;
#pragma unroll
        for (int j = 0; j < 8; ++j) {
            float4 c = *(const float4*)(cw + j * 64);
            float4 v = r4[j];
            v.x -= c.x; v.y -= c.y; v.z -= c.z; v.w -= c.w;
            r4[j] = v;
            ss += v.x * v.x + v.y * v.y + v.z * v.z + v.w * v.w;
        }
        if (g == 0) out[IDX_OFF + (size_t)(tok0 + tl) * NUM_Q + q] = (float)bidx;
#pragma unroll
        for (int off = 32; off >= 1; off >>= 1) ss += __shfl_xor(ss, off, 64);
        if (lane == 0) atomicAdd(out + LOSS_OFF + q, ss * (1.0f / ((float)BN * (float)D)));
        __syncthreads();   // protect red/A before next layer's build
    }

    // ---- finalize: quantized_out = x - residual_final ----
    {
        const float* xr = x + (size_t)(tok0 + tl) * D + g * 4;
        float* qo = out + QOUT_OFF + (size_t)(tok0 + tl) * D + g * 4;
#pragma unroll
        for (int j = 0; j < 8; ++j) {
            float4 xv = *(const float4*)(xr + j * 64);
            float4 v  = r4[j];
            *(float4*)(qo + j * 64) =
                make_float4(xv.x - v.x, xv.y - v.y, xv.z - v.z, xv.w - v.w);
        }
    }
}

extern "C" void kernel_launch(void* const* d_in, const int* in_sizes, int n_in,
                              void* d_out, int out_size, void* d_ws, size_t ws_size,
                              hipStream_t stream) {
    const float* x   = (const float*)d_in[0];
    const float* cbs = (const float*)d_in[1];
    float* out = (float*)d_out;
    _Float16* cbp = (_Float16*)((char*)d_ws + CBP_OFF_B);
    float* e2ws   = (float*)((char*)d_ws + E2_OFF_B);

    hipLaunchKernelGGL(rvq_prep,  dim3(NUM_Q * C / 4), dim3(256), 0, stream, cbs, cbp, e2ws, out);
    hipLaunchKernelGGL(rvq_fused, dim3(BN / 32),       dim3(512), 0, stream, x, cbs, cbp, e2ws, out);
}